// Round 3
// baseline (128.179 us; speedup 1.0000x reference)
//
#include <hip/hip_runtime.h>

typedef __attribute__((ext_vector_type(8))) short short8;
typedef __attribute__((ext_vector_type(4))) short short4v;
typedef __attribute__((ext_vector_type(4))) float f32x4;

__device__ __forceinline__ float bf2f(short s) {
  union { unsigned u; float f; } cv;
  cv.u = ((unsigned)(unsigned short)s) << 16;
  return cv.f;
}
__device__ __forceinline__ short f2bf(float f) {
  union { float f; unsigned u; } cv;
  cv.f = f;
  unsigned r = (cv.u + 0x7fffu + ((cv.u >> 16) & 1u)) >> 16;
  return (short)(unsigned short)r;
}
// byte-XOR key for 16B-slot swizzle within a row (G4): spreads rows over banks
__device__ __forceinline__ int key16(int row) {
  return ((row ^ (row >> 3)) & 7) << 4;
}

#define MFMA16(a, b, c) __builtin_amdgcn_mfma_f32_16x16x32_bf16((a), (b), (c), 0, 0, 0)

// ---------------------------------------------------------------------------
// convert fp32 w_w -> bf16 workspace (32768 elems)
// ---------------------------------------------------------------------------
__global__ __launch_bounds__(256) void cvt_w(const float* __restrict__ s,
                                             short* __restrict__ d)
{
  int i = (blockIdx.x * 256 + threadIdx.x) * 4;
  f32x4 v = *reinterpret_cast<const f32x4*>(s + i);
  short4v o;
  #pragma unroll
  for (int j = 0; j < 4; j++) o[j] = f2bf(v[j]);
  *reinterpret_cast<short4v*>(d + i) = o;
}

// ---------------------------------------------------------------------------
// conv1x1: out[b][p][o] = sum_c in[b][c][p] * w[o][c] + bias[o]
// in: fp32 [b][c][4096]; w: fp32 [o][256] (converted inline); out: bf16 [b][p][o]
// ---------------------------------------------------------------------------
template <int NPROJ>
__global__ __launch_bounds__(256) void conv_proj(
    const float* __restrict__ in,
    const float* __restrict__ w0, const float* __restrict__ bias0,
    const float* __restrict__ w1, const float* __restrict__ bias1,
    short* __restrict__ out0, short* __restrict__ out1)
{
  __shared__ short in_t[64][40];            // [p][c], octet-XOR swizzled
  __shared__ short wt[NPROJ][128][40];      // [o][c], octet-XOR swizzled

  const int b = blockIdx.y;
  const int p0 = blockIdx.x * 64;
  const int tid = threadIdx.x;
  const int wave = tid >> 6, lane = tid & 63;
  const int lr = lane & 15, lg = lane >> 4;

  const float* wsrc[2] = {w0, w1};

  f32x4 acc[NPROJ][8];
  #pragma unroll
  for (int pj = 0; pj < NPROJ; pj++)
    #pragma unroll
    for (int n = 0; n < 8; n++) acc[pj][n] = (f32x4)0.0f;

  for (int kc = 0; kc < 256; kc += 32) {
    __syncthreads();
    {
      int c = tid >> 3;                 // 0..31
      int pg = (tid & 7) * 8;           // pixel group
      const float* src = in + ((size_t)(b * 256 + kc + c)) * 4096 + p0 + pg;
      f32x4 v0 = *reinterpret_cast<const f32x4*>(src);
      f32x4 v1 = *reinterpret_cast<const f32x4*>(src + 4);
      #pragma unroll
      for (int j = 0; j < 8; j++) {
        int p = pg + j;
        float fv = (j < 4) ? v0[j] : v1[j - 4];
        in_t[p][c ^ ((((p >> 3) & 3)) << 3)] = f2bf(fv);
      }
    }
    for (int idx = tid; idx < NPROJ * 128; idx += 256) {
      int pj = idx >> 7, o = idx & 127;
      const float* src = wsrc[pj] + (size_t)o * 256 + kc;
      int f = (o >> 3) & 3;
      #pragma unroll
      for (int gq = 0; gq < 4; gq++) {
        f32x4 a = *reinterpret_cast<const f32x4*>(src + gq * 8);
        f32x4 c2 = *reinterpret_cast<const f32x4*>(src + gq * 8 + 4);
        short8 v;
        #pragma unroll
        for (int j = 0; j < 4; j++) { v[j] = f2bf(a[j]); v[4 + j] = f2bf(c2[j]); }
        *reinterpret_cast<short8*>(&wt[pj][o][(gq ^ f) * 8]) = v;
      }
    }
    __syncthreads();

    int arow = wave * 16 + lr;
    short8 afrag = *reinterpret_cast<const short8*>(
        &in_t[arow][(lg ^ ((arow >> 3) & 3)) * 8]);
    #pragma unroll
    for (int pj = 0; pj < NPROJ; pj++) {
      #pragma unroll
      for (int n = 0; n < 8; n++) {
        int brow = n * 16 + lr;
        short8 bfrag = *reinterpret_cast<const short8*>(
            &wt[pj][brow][(lg ^ ((brow >> 3) & 3)) * 8]);
        acc[pj][n] = MFMA16(afrag, bfrag, acc[pj][n]);
      }
    }
  }

  const float* bsrc[2] = {bias0, bias1};
  short* osrc[2] = {out0, out1};
  #pragma unroll
  for (int pj = 0; pj < NPROJ; pj++) {
    #pragma unroll
    for (int n = 0; n < 8; n++) {
      int o = n * 16 + lr;
      float bv = bsrc[pj][o];
      #pragma unroll
      for (int r = 0; r < 4; r++) {
        int prow = p0 + wave * 16 + lg * 4 + r;
        osrc[pj][((size_t)b * 4096 + prow) * 128 + o] = f2bf(acc[pj][n][r] + bv);
      }
    }
  }
}

// ---------------------------------------------------------------------------
// maxpool 2x2: src bf16 [b][p=4096][128] -> dst bf16 [b][kp=1024][128]
// ---------------------------------------------------------------------------
__global__ __launch_bounds__(256) void pool_phi_k(const short* __restrict__ src,
                                                  short* __restrict__ dst)
{
  int b = blockIdx.y;
  int kp = blockIdx.x * 16 + (threadIdx.x >> 4);
  int o8 = (threadIdx.x & 15) * 8;
  int ph = kp >> 5, pw = kp & 31;
  size_t base = ((size_t)b * 4096 + ph * 128 + pw * 2) * 128 + o8;
  short8 v0 = *reinterpret_cast<const short8*>(src + base);
  short8 v1 = *reinterpret_cast<const short8*>(src + base + 128);
  short8 v2 = *reinterpret_cast<const short8*>(src + base + 64 * 128);
  short8 v3 = *reinterpret_cast<const short8*>(src + base + 65 * 128);
  short8 o;
  #pragma unroll
  for (int j = 0; j < 8; j++) {
    float m = fmaxf(fmaxf(bf2f(v0[j]), bf2f(v1[j])), fmaxf(bf2f(v2[j]), bf2f(v3[j])));
    o[j] = f2bf(m);
  }
  *reinterpret_cast<short8*>(dst + ((size_t)b * 1024 + kp) * 128 + o8) = o;
}

// ---------------------------------------------------------------------------
// maxpool 2x2 + transpose: src bf16 [b][p=4096][128] -> dst bf16 [b][128][kp=1024]
// ---------------------------------------------------------------------------
__global__ __launch_bounds__(256) void pool_g_t(const short* __restrict__ src,
                                                short* __restrict__ dst)
{
  __shared__ short s[32][136];
  int b = blockIdx.y;
  int kp0 = blockIdx.x * 32;
  int t = threadIdx.x;
  {
    int kpl = t >> 3;
    int o0 = (t & 7) * 16;
    int kp = kp0 + kpl;
    int ph = kp >> 5, pw = kp & 31;
    size_t base = ((size_t)b * 4096 + ph * 128 + pw * 2) * 128;
    #pragma unroll
    for (int h = 0; h < 2; h++) {
      int oo = o0 + h * 8;
      short8 v0 = *reinterpret_cast<const short8*>(src + base + oo);
      short8 v1 = *reinterpret_cast<const short8*>(src + base + 128 + oo);
      short8 v2 = *reinterpret_cast<const short8*>(src + base + 64 * 128 + oo);
      short8 v3 = *reinterpret_cast<const short8*>(src + base + 65 * 128 + oo);
      #pragma unroll
      for (int j = 0; j < 8; j++) {
        float m = fmaxf(fmaxf(bf2f(v0[j]), bf2f(v1[j])), fmaxf(bf2f(v2[j]), bf2f(v3[j])));
        s[kpl][oo + j] = f2bf(m);
      }
    }
  }
  __syncthreads();
  {
    int o = t >> 1;
    int k0 = (t & 1) * 16;
    short8 v0, v1;
    #pragma unroll
    for (int j = 0; j < 8; j++) { v0[j] = s[k0 + j][o]; v1[j] = s[k0 + 8 + j][o]; }
    *reinterpret_cast<short8*>(dst + ((size_t)b * 128 + o) * 1024 + kp0 + k0) = v0;
    *reinterpret_cast<short8*>(dst + ((size_t)b * 128 + o) * 1024 + kp0 + k0 + 8) = v1;
  }
}

// ---------------------------------------------------------------------------
// flash attention v2: Q in regs, phi/g double-buffered LDS (reg-staged,
// issue-early/write-late), XOR slot swizzle, 1 barrier/iter, per-lane
// partial row-sums, skip-rescale. 4 waves x 16 q rows, KVBLK=64, 16 iters.
// ---------------------------------------------------------------------------
__global__ __launch_bounds__(256) void attn(
    const short* __restrict__ theta, const short* __restrict__ phi,
    const short* __restrict__ g, short* __restrict__ y)
{
  __shared__ short phi_s[2][64][128];   // [buf][kv][ci], rows 256B, swizzled
  __shared__ short g_s[2][128][64];     // [buf][ci][kv], rows 128B, swizzled
  __shared__ short p_s[4][16][64];      // per-wave [q][kv], rows 128B, swizzled

  const int b = blockIdx.y;
  const int q0 = blockIdx.x * 64;
  const int tid = threadIdx.x;
  const int wave = tid >> 6, lane = tid & 63;
  const int lr = lane & 15, lg = lane >> 4;

  // Q fragments in registers (4 K-slices of 32)
  short8 ath[4];
  {
    const short* tq = theta + ((size_t)b * 4096 + q0 + wave * 16 + lr) * 128 + lg * 8;
    #pragma unroll
    for (int kk = 0; kk < 4; kk++)
      ath[kk] = *reinterpret_cast<const short8*>(tq + kk * 32);
  }

  // staging addresses (per thread: 64B of phi tile, 64B of g tile)
  const int pr = tid >> 2, pcq = tid & 3;        // phi: row 0..63, quarter 0..3
  const int gr = tid >> 1, ghq = tid & 1;        // g: row 0..127, half 0..1
  const short* phi_src = phi + ((size_t)b * 1024 + pr) * 128 + pcq * 32;
  const short* g_src   = g + ((size_t)b * 128 + gr) * 1024 + ghq * 32;
  const int pkr = key16(pr), gkr = key16(gr);

  short8 sphi[4], sg[4];
  #pragma unroll
  for (int j = 0; j < 4; j++) {
    sphi[j] = *reinterpret_cast<const short8*>(phi_src + j * 8);
    sg[j]   = *reinterpret_cast<const short8*>(g_src + j * 8);
  }

  float mrun[4], lpart[4];
  #pragma unroll
  for (int r = 0; r < 4; r++) { mrun[r] = -1e30f; lpart[r] = 0.0f; }
  f32x4 acc[8];
  #pragma unroll
  for (int n = 0; n < 8; n++) acc[n] = (f32x4)0.0f;

  char* const pbase = (char*)&p_s[wave][0][0];
  const int klr = key16(lr);
  const int prow = lg * 4;           // this lane's first p-row
  const int kprow0 = key16(prow), kprow1 = key16(prow + 1),
            kprow2 = key16(prow + 2), kprow3 = key16(prow + 3);
  const int kpr[4] = {kprow0, kprow1, kprow2, kprow3};

  for (int t = 0; t < 16; t++) {
    const int buf = t & 1;
    char* phib = (char*)&phi_s[buf][0][0];
    char* gbse = (char*)&g_s[buf][0][0];
    // write staged tile t into buf
    #pragma unroll
    for (int j = 0; j < 4; j++) {
      *reinterpret_cast<short8*>(phib + pr * 256 + ((pcq * 64 + j * 16) ^ pkr)) = sphi[j];
      *reinterpret_cast<short8*>(gbse + gr * 128 + ((ghq * 64 + j * 16) ^ gkr)) = sg[j];
    }
    __syncthreads();

    // issue loads for tile t+1 (hidden under compute)
    if (t < 15) {
      const short* ps = phi_src + (t + 1) * 64 * 128;
      const short* gs = g_src + (t + 1) * 64;
      #pragma unroll
      for (int j = 0; j < 4; j++) {
        sphi[j] = *reinterpret_cast<const short8*>(ps + j * 8);
        sg[j]   = *reinterpret_cast<const short8*>(gs + j * 8);
      }
    }

    // QK^T: 16 q rows x 64 kv
    f32x4 facc[4];
    #pragma unroll
    for (int n = 0; n < 4; n++) facc[n] = (f32x4)0.0f;
    #pragma unroll
    for (int kk = 0; kk < 4; kk++) {
      #pragma unroll
      for (int n = 0; n < 4; n++) {
        int row = n * 16 + lr;
        short8 bfrag = *reinterpret_cast<const short8*>(
            phib + row * 256 + ((kk * 64 + lg * 16) ^ key16(row)));
        facc[n] = MFMA16(ath[kk], bfrag, facc[n]);
      }
    }

    // online softmax
    float mx[4], mn[4];
    #pragma unroll
    for (int r = 0; r < 4; r++) {
      float m = fmaxf(fmaxf(facc[0][r], facc[1][r]), fmaxf(facc[2][r], facc[3][r]));
      #pragma unroll
      for (int off = 8; off >= 1; off >>= 1) m = fmaxf(m, __shfl_xor(m, off));
      mx[r] = m;
      mn[r] = fmaxf(mrun[r], m);
    }
    bool up = (mn[0] > mrun[0]) | (mn[1] > mrun[1]) | (mn[2] > mrun[2]) | (mn[3] > mrun[3]);
    if (__any(up)) {
      #pragma unroll
      for (int r = 0; r < 4; r++) {
        float sc = __expf(mrun[r] - mn[r]);
        mrun[r] = mn[r];
        lpart[r] *= sc;
        #pragma unroll
        for (int n = 0; n < 8; n++) acc[n][r] *= sc;
      }
    }
    // P = exp(S - m), per-lane partial sums, write bf16 to p_s
    #pragma unroll
    for (int r = 0; r < 4; r++) {
      #pragma unroll
      for (int n = 0; n < 4; n++) {
        float pv = __expf(facc[n][r] - mrun[r]);
        lpart[r] += pv;
        *reinterpret_cast<short*>(
            pbase + (prow + r) * 128 + ((n * 32 + lr * 2) ^ kpr[r])) = f2bf(pv);
      }
    }

    // y += P . g^T  (in-wave p_s RAW; DS unit keeps per-wave order)
    #pragma unroll
    for (int kk = 0; kk < 2; kk++) {
      short8 pa = *reinterpret_cast<const short8*>(
          pbase + lr * 128 + ((kk * 64 + lg * 16) ^ klr));
      #pragma unroll
      for (int n = 0; n < 8; n++) {
        int row = n * 16 + lr;
        short8 gfrag = *reinterpret_cast<const short8*>(
            gbse + row * 128 + ((kk * 64 + lg * 16) ^ key16(row)));
        acc[n] = MFMA16(pa, gfrag, acc[n]);
      }
    }
  }

  // final row sums across lr lanes
  float lsum[4];
  #pragma unroll
  for (int r = 0; r < 4; r++) {
    float s = lpart[r];
    #pragma unroll
    for (int off = 8; off >= 1; off >>= 1) s += __shfl_xor(s, off);
    lsum[r] = 1.0f / s;
  }

  #pragma unroll
  for (int n = 0; n < 8; n++) {
    #pragma unroll
    for (int r = 0; r < 4; r++) {
      int q = q0 + wave * 16 + lg * 4 + r;
      y[((size_t)b * 4096 + q) * 128 + n * 16 + lr] = f2bf(acc[n][r] * lsum[r]);
    }
  }
}

// ---------------------------------------------------------------------------
// wy = w_w . y (per pixel) + bias, BN (eval), + x  -> out fp32 [b][256][4096]
// ---------------------------------------------------------------------------
__global__ __launch_bounds__(256) void wconv_bn(
    const short* __restrict__ y, const short* __restrict__ ww,
    const float* __restrict__ wb,
    const float* __restrict__ gamma, const float* __restrict__ beta,
    const float* __restrict__ mean, const float* __restrict__ var,
    const float* __restrict__ x, float* __restrict__ out)
{
  __shared__ short y_s[64][136];
  __shared__ float sc_s[256];
  __shared__ float sh_s[256];

  const int b = blockIdx.y;
  const int q0 = blockIdx.x * 64;
  const int tid = threadIdx.x;
  const int wave = tid >> 6, lane = tid & 63;
  const int lr = lane & 15, lg = lane >> 4;

  {
    int r = tid >> 2, c0 = (tid & 3) * 32;
    const short8* src = reinterpret_cast<const short8*>(
        y + ((size_t)b * 4096 + q0 + r) * 128 + c0);
    short8* dstv = reinterpret_cast<short8*>(&y_s[r][c0]);
    #pragma unroll
    for (int j = 0; j < 4; j++) dstv[j] = src[j];
    float s = gamma[tid] * rsqrtf(var[tid] + 1e-5f);
    sc_s[tid] = s;
    sh_s[tid] = (wb[tid] - mean[tid]) * s + beta[tid];
  }
  __syncthreads();

  f32x4 acc[4][4];
  #pragma unroll
  for (int m = 0; m < 4; m++)
    #pragma unroll
    for (int n = 0; n < 4; n++) acc[m][n] = (f32x4)0.0f;

  #pragma unroll
  for (int kk = 0; kk < 4; kk++) {
    short8 af[4], bfr[4];
    #pragma unroll
    for (int m = 0; m < 4; m++)
      af[m] = *reinterpret_cast<const short8*>(
          ww + (size_t)(wave * 64 + m * 16 + lr) * 128 + kk * 32 + lg * 8);
    #pragma unroll
    for (int n = 0; n < 4; n++)
      bfr[n] = *reinterpret_cast<const short8*>(&y_s[n * 16 + lr][kk * 32 + lg * 8]);
    #pragma unroll
    for (int m = 0; m < 4; m++)
      #pragma unroll
      for (int n = 0; n < 4; n++)
        acc[m][n] = MFMA16(af[m], bfr[n], acc[m][n]);
  }

  #pragma unroll
  for (int m = 0; m < 4; m++) {
    #pragma unroll
    for (int n = 0; n < 4; n++) {
      #pragma unroll
      for (int r = 0; r < 4; r++) {
        int co = wave * 64 + m * 16 + lg * 4 + r;
        int q = q0 + n * 16 + lr;
        size_t oidx = ((size_t)b * 256 + co) * 4096 + q;
        float v = acc[m][n][r] * sc_s[co] + sh_s[co];
        out[oidx] = v + x[oidx];
      }
    }
  }
}

// ---------------------------------------------------------------------------
extern "C" void kernel_launch(void* const* d_in, const int* in_sizes, int n_in,
                              void* d_out, int out_size, void* d_ws, size_t ws_size,
                              hipStream_t stream)
{
  const float* x    = (const float*)d_in[0];
  const float* nb   = (const float*)d_in[1];
  const float* g_w  = (const float*)d_in[2];
  const float* g_b  = (const float*)d_in[3];
  const float* th_w = (const float*)d_in[4];
  const float* th_b = (const float*)d_in[5];
  const float* ph_w = (const float*)d_in[6];
  const float* ph_b = (const float*)d_in[7];
  const float* w_w  = (const float*)d_in[8];
  const float* w_b  = (const float*)d_in[9];
  const float* gam  = (const float*)d_in[10];
  const float* bet  = (const float*)d_in[11];
  const float* mu   = (const float*)d_in[12];
  const float* var  = (const float*)d_in[13];
  float* out = (float*)d_out;

  char* ws = (char*)d_ws;
  short* theta_full = (short*)(ws);                        // 8 MB  [b][4096][128]
  short* phi_full   = (short*)(ws + (size_t)(8u << 20));   // 8 MB  [b][4096][128]
  short* g_full     = (short*)(ws + (size_t)(16u << 20));  // 8 MB  [b][4096][128]
  short* phi_kc     = (short*)(ws + (size_t)(24u << 20));  // 2 MB  [b][1024][128]
  short* g_ck       = (short*)(ws + (size_t)(26u << 20));  // 2 MB  [b][128][1024]
  short* yb         = (short*)(ws + (size_t)(28u << 20));  // 8 MB  [b][4096][128]
  short* w_wb       = (short*)(ws + (size_t)(36u << 20));  // 64 KB

  cvt_w<<<dim3(32), 256, 0, stream>>>(w_w, w_wb);
  conv_proj<2><<<dim3(64, 8), 256, 0, stream>>>(nb, th_w, th_b, ph_w, ph_b,
                                                theta_full, phi_full);
  conv_proj<1><<<dim3(64, 8), 256, 0, stream>>>(x, g_w, g_b, nullptr, nullptr,
                                                g_full, nullptr);
  pool_phi_k<<<dim3(64, 8), 256, 0, stream>>>(phi_full, phi_kc);
  pool_g_t<<<dim3(32, 8), 256, 0, stream>>>(g_full, g_ck);
  attn<<<dim3(64, 8), 256, 0, stream>>>(theta_full, phi_kc, g_ck, yb);
  wconv_bn<<<dim3(64, 8), 256, 0, stream>>>(yb, w_wb, w_b, gam, bet, mu, var, x, out);
}

// Round 4
// 118.091 us; speedup vs baseline: 1.0854x; 1.0854x over previous
//
#include <hip/hip_runtime.h>

typedef __attribute__((ext_vector_type(8))) short short8;
typedef __attribute__((ext_vector_type(4))) short short4v;
typedef __attribute__((ext_vector_type(4))) float f32x4;

__device__ __forceinline__ float bf2f(short s) {
  union { unsigned u; float f; } cv;
  cv.u = ((unsigned)(unsigned short)s) << 16;
  return cv.f;
}
__device__ __forceinline__ short f2bf(float f) {
  union { float f; unsigned u; } cv;
  cv.f = f;
  unsigned r = (cv.u + 0x7fffu + ((cv.u >> 16) & 1u)) >> 16;
  return (short)(unsigned short)r;
}

#define MFMA16(a, b, c) __builtin_amdgcn_mfma_f32_16x16x32_bf16((a), (b), (c), 0, 0, 0)

// ---------------------------------------------------------------------------
// convert fp32 weight matrices -> bf16 workspace. 4 matrices x 32768 elems.
// ---------------------------------------------------------------------------
__global__ __launch_bounds__(256) void cvt_w(
    const float* __restrict__ s0, const float* __restrict__ s1,
    const float* __restrict__ s2, const float* __restrict__ s3,
    short* __restrict__ d)
{
  const float* srcs[4] = {s0, s1, s2, s3};
  const float* s = srcs[blockIdx.y];
  int i = (blockIdx.x * 256 + threadIdx.x) * 4;
  f32x4 v = *reinterpret_cast<const f32x4*>(s + i);
  short4v o;
  #pragma unroll
  for (int j = 0; j < 4; j++) o[j] = f2bf(v[j]);
  *reinterpret_cast<short4v*>(d + (size_t)blockIdx.y * 32768 + i) = o;
}

// ---------------------------------------------------------------------------
// conv1x1: out[b][p][o] = sum_c in[b][c][p] * w[o][c] + bias[o]
// in: fp32 [b][c][4096]; w: bf16 [o][256] (pre-converted); out: bf16 [b][p][o]
// ---------------------------------------------------------------------------
template <int NPROJ>
__global__ __launch_bounds__(256) void conv_proj(
    const float* __restrict__ in,
    const short* __restrict__ w0, const float* __restrict__ bias0,
    const short* __restrict__ w1, const float* __restrict__ bias1,
    short* __restrict__ out0, short* __restrict__ out1)
{
  __shared__ short in_t[64][40];            // [p][c], octet-XOR swizzled
  __shared__ short wt[NPROJ][128][40];      // [o][c], octet-XOR swizzled

  const int b = blockIdx.y;
  const int p0 = blockIdx.x * 64;
  const int tid = threadIdx.x;
  const int wave = tid >> 6, lane = tid & 63;
  const int lr = lane & 15, lg = lane >> 4;

  const short* wsrc[2] = {w0, w1};

  f32x4 acc[NPROJ][8];
  #pragma unroll
  for (int pj = 0; pj < NPROJ; pj++)
    #pragma unroll
    for (int n = 0; n < 8; n++) acc[pj][n] = (f32x4)0.0f;

  for (int kc = 0; kc < 256; kc += 32) {
    __syncthreads();
    {
      int c = tid >> 3;                 // 0..31
      int pg = (tid & 7) * 8;           // pixel group
      const float* src = in + ((size_t)(b * 256 + kc + c)) * 4096 + p0 + pg;
      f32x4 v0 = *reinterpret_cast<const f32x4*>(src);
      f32x4 v1 = *reinterpret_cast<const f32x4*>(src + 4);
      #pragma unroll
      for (int j = 0; j < 8; j++) {
        int p = pg + j;
        float fv = (j < 4) ? v0[j] : v1[j - 4];
        in_t[p][c ^ ((((p >> 3) & 3)) << 3)] = f2bf(fv);
      }
    }
    for (int idx = tid; idx < NPROJ * 128; idx += 256) {
      int pj = idx >> 7, o = idx & 127;
      const short8* src = reinterpret_cast<const short8*>(wsrc[pj] + (size_t)o * 256 + kc);
      int f = (o >> 3) & 3;
      #pragma unroll
      for (int gq = 0; gq < 4; gq++)
        *reinterpret_cast<short8*>(&wt[pj][o][(gq ^ f) * 8]) = src[gq];
    }
    __syncthreads();

    int arow = wave * 16 + lr;
    short8 afrag = *reinterpret_cast<const short8*>(
        &in_t[arow][(lg ^ ((arow >> 3) & 3)) * 8]);
    #pragma unroll
    for (int pj = 0; pj < NPROJ; pj++) {
      #pragma unroll
      for (int n = 0; n < 8; n++) {
        int brow = n * 16 + lr;
        short8 bfrag = *reinterpret_cast<const short8*>(
            &wt[pj][brow][(lg ^ ((brow >> 3) & 3)) * 8]);
        acc[pj][n] = MFMA16(afrag, bfrag, acc[pj][n]);
      }
    }
  }

  const float* bsrc[2] = {bias0, bias1};
  short* osrc[2] = {out0, out1};
  #pragma unroll
  for (int pj = 0; pj < NPROJ; pj++) {
    #pragma unroll
    for (int n = 0; n < 8; n++) {
      int o = n * 16 + lr;
      float bv = bsrc[pj][o];
      #pragma unroll
      for (int r = 0; r < 4; r++) {
        int prow = p0 + wave * 16 + lg * 4 + r;
        osrc[pj][((size_t)b * 4096 + prow) * 128 + o] = f2bf(acc[pj][n][r] + bv);
      }
    }
  }
}

// ---------------------------------------------------------------------------
// maxpool 2x2: src bf16 [b][p=4096][128] -> dst bf16 [b][kp=1024][128]
// ---------------------------------------------------------------------------
__global__ __launch_bounds__(256) void pool_phi_k(const short* __restrict__ src,
                                                  short* __restrict__ dst)
{
  int b = blockIdx.y;
  int kp = blockIdx.x * 16 + (threadIdx.x >> 4);
  int o8 = (threadIdx.x & 15) * 8;
  int ph = kp >> 5, pw = kp & 31;
  size_t base = ((size_t)b * 4096 + ph * 128 + pw * 2) * 128 + o8;
  short8 v0 = *reinterpret_cast<const short8*>(src + base);
  short8 v1 = *reinterpret_cast<const short8*>(src + base + 128);
  short8 v2 = *reinterpret_cast<const short8*>(src + base + 64 * 128);
  short8 v3 = *reinterpret_cast<const short8*>(src + base + 65 * 128);
  short8 o;
  #pragma unroll
  for (int j = 0; j < 8; j++) {
    float m = fmaxf(fmaxf(bf2f(v0[j]), bf2f(v1[j])), fmaxf(bf2f(v2[j]), bf2f(v3[j])));
    o[j] = f2bf(m);
  }
  *reinterpret_cast<short8*>(dst + ((size_t)b * 1024 + kp) * 128 + o8) = o;
}

// ---------------------------------------------------------------------------
// maxpool 2x2 + transpose: src bf16 [b][p=4096][128] -> dst bf16 [b][128][kp=1024]
// ---------------------------------------------------------------------------
__global__ __launch_bounds__(256) void pool_g_t(const short* __restrict__ src,
                                                short* __restrict__ dst)
{
  __shared__ short s[32][136];
  int b = blockIdx.y;
  int kp0 = blockIdx.x * 32;
  int t = threadIdx.x;
  {
    int kpl = t >> 3;
    int o0 = (t & 7) * 16;
    int kp = kp0 + kpl;
    int ph = kp >> 5, pw = kp & 31;
    size_t base = ((size_t)b * 4096 + ph * 128 + pw * 2) * 128;
    #pragma unroll
    for (int h = 0; h < 2; h++) {
      int oo = o0 + h * 8;
      short8 v0 = *reinterpret_cast<const short8*>(src + base + oo);
      short8 v1 = *reinterpret_cast<const short8*>(src + base + 128 + oo);
      short8 v2 = *reinterpret_cast<const short8*>(src + base + 64 * 128 + oo);
      short8 v3 = *reinterpret_cast<const short8*>(src + base + 65 * 128 + oo);
      #pragma unroll
      for (int j = 0; j < 8; j++) {
        float m = fmaxf(fmaxf(bf2f(v0[j]), bf2f(v1[j])), fmaxf(bf2f(v2[j]), bf2f(v3[j])));
        s[kpl][oo + j] = f2bf(m);
      }
    }
  }
  __syncthreads();
  {
    int o = t >> 1;
    int k0 = (t & 1) * 16;
    short8 v0, v1;
    #pragma unroll
    for (int j = 0; j < 8; j++) { v0[j] = s[k0 + j][o]; v1[j] = s[k0 + 8 + j][o]; }
    *reinterpret_cast<short8*>(dst + ((size_t)b * 128 + o) * 1024 + kp0 + k0) = v0;
    *reinterpret_cast<short8*>(dst + ((size_t)b * 128 + o) * 1024 + kp0 + k0 + 8) = v1;
  }
}

// ---------------------------------------------------------------------------
// flash attention v3: QBLK=128 (4 waves x 32 q), KVBLK=64.
// Swapped QK^T (mfma(phi, theta) -> S^T) so each lane owns P column q=lr:
// in-lane 16-value max trees + 2 shuffles; P packed to b64 LDS writes,
// read back as b128 A-frags. Exact-involution XOR swizzles on all tiles.
// Double-buffered reg-staged phi/g, 1 barrier/iter.
// ---------------------------------------------------------------------------
__global__ __launch_bounds__(256) void attn(
    const short* __restrict__ theta, const short* __restrict__ phi,
    const short* __restrict__ g, short* __restrict__ y)
{
  __shared__ short phi_s[2][64][128];   // rows 256B = 16 slots, key = kv&15
  __shared__ short g_s[2][128][64];     // rows 128B = 8 slots,  key = ci&7
  __shared__ short p_s[4][32][64];      // per-wave, rows 128B,  key = q&7

  const int b = blockIdx.y;
  const int q0 = blockIdx.x * 128;
  const int tid = threadIdx.x;
  const int wave = tid >> 6, lane = tid & 63;
  const int lr = lane & 15, lg = lane >> 4;

  // theta fragments (32 q rows per wave: two 16-row halves)
  short8 ath[2][4];
  {
    const short* tq = theta + ((size_t)b * 4096 + q0 + wave * 32 + lr) * 128 + lg * 8;
    #pragma unroll
    for (int qh = 0; qh < 2; qh++)
      #pragma unroll
      for (int kk = 0; kk < 4; kk++)
        ath[qh][kk] = *reinterpret_cast<const short8*>(tq + qh * 16 * 128 + kk * 32);
  }

  // staging: thread covers 64B of phi tile and 64B of g tile (linear global)
  const int pr = tid >> 2, pcq = tid & 3;     // phi row 0..63, quarter
  const int gr = tid >> 1, ghq = tid & 1;     // g row 0..127, half
  const short* phi_src = phi + ((size_t)b * 1024 + pr) * 128 + pcq * 32;
  const short* g_src   = g + ((size_t)b * 128 + gr) * 1024 + ghq * 32;

  short8 sphi[4], sg[4];
  #pragma unroll
  for (int j = 0; j < 4; j++) {
    sphi[j] = *reinterpret_cast<const short8*>(phi_src + j * 8);
    sg[j]   = *reinterpret_cast<const short8*>(g_src + j * 8);
  }

  float mrun[2] = {-1e30f, -1e30f}, lpart[2] = {0.0f, 0.0f};
  f32x4 acc[2][8];
  #pragma unroll
  for (int qh = 0; qh < 2; qh++)
    #pragma unroll
    for (int n = 0; n < 8; n++) acc[qh][n] = (f32x4)0.0f;

  char* const pbase = (char*)&p_s[wave][0][0];
  const int pkey = (lr & 7) << 4;

  for (int t = 0; t < 16; t++) {
    char* phib = (char*)&phi_s[t & 1][0][0];
    char* gbse = (char*)&g_s[t & 1][0][0];
    // write staged tile t (swizzled slots)
    #pragma unroll
    for (int j = 0; j < 4; j++) {
      *reinterpret_cast<short8*>(phib + pr * 256 + (((pcq * 4 + j) ^ (pr & 15)) * 16)) = sphi[j];
      *reinterpret_cast<short8*>(gbse + gr * 128 + (((ghq * 4 + j) ^ (gr & 7)) * 16)) = sg[j];
    }
    __syncthreads();

    // issue loads for tile t+1
    if (t < 15) {
      const short* ps = phi_src + (t + 1) * 64 * 128;
      const short* gs = g_src + (t + 1) * 64;
      #pragma unroll
      for (int j = 0; j < 4; j++) {
        sphi[j] = *reinterpret_cast<const short8*>(ps + j * 8);
        sg[j]   = *reinterpret_cast<const short8*>(gs + j * 8);
      }
    }

    // QK^T swapped: facc[qh][n] = S^T tile [kv=16n..][q=qh*16..]
    f32x4 facc[2][4];
    #pragma unroll
    for (int qh = 0; qh < 2; qh++)
      #pragma unroll
      for (int n = 0; n < 4; n++) facc[qh][n] = (f32x4)0.0f;
    #pragma unroll
    for (int kk = 0; kk < 4; kk++) {
      #pragma unroll
      for (int n = 0; n < 4; n++) {
        int row = n * 16 + lr;
        short8 pf = *reinterpret_cast<const short8*>(
            phib + row * 256 + (((4 * kk + lg) ^ (row & 15)) * 16));
        facc[0][n] = MFMA16(pf, ath[0][kk], facc[0][n]);
        facc[1][n] = MFMA16(pf, ath[1][kk], facc[1][n]);
      }
    }

    // online softmax: lane owns q = qh*16+lr, 16 in-lane kv values
    float mnew[2];
    #pragma unroll
    for (int qh = 0; qh < 2; qh++) {
      float m0 = fmaxf(fmaxf(facc[qh][0][0], facc[qh][0][1]), fmaxf(facc[qh][0][2], facc[qh][0][3]));
      float m1 = fmaxf(fmaxf(facc[qh][1][0], facc[qh][1][1]), fmaxf(facc[qh][1][2], facc[qh][1][3]));
      float m2 = fmaxf(fmaxf(facc[qh][2][0], facc[qh][2][1]), fmaxf(facc[qh][2][2], facc[qh][2][3]));
      float m3 = fmaxf(fmaxf(facc[qh][3][0], facc[qh][3][1]), fmaxf(facc[qh][3][2], facc[qh][3][3]));
      float m = fmaxf(fmaxf(m0, m1), fmaxf(m2, m3));
      m = fmaxf(m, __shfl_xor(m, 16));
      m = fmaxf(m, __shfl_xor(m, 32));
      mnew[qh] = fmaxf(mrun[qh], m);
    }
    bool upd = (mnew[0] > mrun[0]) | (mnew[1] > mrun[1]);
    if (__any(upd)) {
      float sc0 = __expf(mrun[0] - mnew[0]);
      float sc1 = __expf(mrun[1] - mnew[1]);
      mrun[0] = mnew[0]; mrun[1] = mnew[1];
      lpart[0] *= sc0; lpart[1] *= sc1;
      #pragma unroll
      for (int r = 0; r < 4; r++) {
        float s0 = __shfl(sc0, lg * 4 + r);
        float s1 = __shfl(sc1, lg * 4 + r);
        #pragma unroll
        for (int n = 0; n < 8; n++) { acc[0][n][r] *= s0; acc[1][n][r] *= s1; }
      }
    }
    // P = exp(S - m): pack 4 kv values -> one b64 write per (qh, n)
    #pragma unroll
    for (int qh = 0; qh < 2; qh++) {
      #pragma unroll
      for (int n = 0; n < 4; n++) {
        float e0 = __expf(facc[qh][n][0] - mrun[qh]);
        float e1 = __expf(facc[qh][n][1] - mrun[qh]);
        float e2 = __expf(facc[qh][n][2] - mrun[qh]);
        float e3 = __expf(facc[qh][n][3] - mrun[qh]);
        lpart[qh] += (e0 + e1) + (e2 + e3);
        short4v pk;
        pk[0] = f2bf(e0); pk[1] = f2bf(e1); pk[2] = f2bf(e2); pk[3] = f2bf(e3);
        *reinterpret_cast<short4v*>(
            pbase + (qh * 16 + lr) * 128 + ((n * 32 + lg * 8) ^ pkey)) = pk;
      }
    }

    // y^T accumulate: acc[qh][n] += P[qh] . g  (A from p_s, B from g_s)
    #pragma unroll
    for (int kk = 0; kk < 2; kk++) {
      short8 pa0 = *reinterpret_cast<const short8*>(
          pbase + lr * 128 + ((kk * 64 + lg * 16) ^ pkey));
      short8 pa1 = *reinterpret_cast<const short8*>(
          pbase + (16 + lr) * 128 + ((kk * 64 + lg * 16) ^ pkey));
      #pragma unroll
      for (int n = 0; n < 8; n++) {
        int row = n * 16 + lr;
        short8 gf = *reinterpret_cast<const short8*>(
            gbse + row * 128 + (((4 * kk + lg) ^ (row & 7)) * 16));
        acc[0][n] = MFMA16(pa0, gf, acc[0][n]);
        acc[1][n] = MFMA16(pa1, gf, acc[1][n]);
      }
    }
    __syncthreads();
  }

  // final denominators: reduce lpart across lg groups, broadcast per acc row
  float linvq[2][4];
  #pragma unroll
  for (int qh = 0; qh < 2; qh++) {
    float s = lpart[qh];
    s += __shfl_xor(s, 16);
    s += __shfl_xor(s, 32);
    float inv = 1.0f / s;
    #pragma unroll
    for (int r = 0; r < 4; r++) linvq[qh][r] = __shfl(inv, lg * 4 + r);
  }

  #pragma unroll
  for (int qh = 0; qh < 2; qh++) {
    #pragma unroll
    for (int n = 0; n < 8; n++) {
      #pragma unroll
      for (int r = 0; r < 4; r++) {
        int q = q0 + wave * 32 + qh * 16 + lg * 4 + r;
        y[((size_t)b * 4096 + q) * 128 + n * 16 + lr] = f2bf(acc[qh][n][r] * linvq[qh][r]);
      }
    }
  }
}

// ---------------------------------------------------------------------------
// wy = w_w . y (per pixel) + bias, BN (eval), + x  -> out fp32 [b][256][4096]
// ---------------------------------------------------------------------------
__global__ __launch_bounds__(256) void wconv_bn(
    const short* __restrict__ y, const short* __restrict__ ww,
    const float* __restrict__ wb,
    const float* __restrict__ gamma, const float* __restrict__ beta,
    const float* __restrict__ mean, const float* __restrict__ var,
    const float* __restrict__ x, float* __restrict__ out)
{
  __shared__ short y_s[64][136];
  __shared__ float sc_s[256];
  __shared__ float sh_s[256];

  const int b = blockIdx.y;
  const int q0 = blockIdx.x * 64;
  const int tid = threadIdx.x;
  const int wave = tid >> 6, lane = tid & 63;
  const int lr = lane & 15, lg = lane >> 4;

  {
    int r = tid >> 2, c0 = (tid & 3) * 32;
    const short8* src = reinterpret_cast<const short8*>(
        y + ((size_t)b * 4096 + q0 + r) * 128 + c0);
    short8* dstv = reinterpret_cast<short8*>(&y_s[r][c0]);
    #pragma unroll
    for (int j = 0; j < 4; j++) dstv[j] = src[j];
    float s = gamma[tid] * rsqrtf(var[tid] + 1e-5f);
    sc_s[tid] = s;
    sh_s[tid] = (wb[tid] - mean[tid]) * s + beta[tid];
  }
  __syncthreads();

  f32x4 acc[4][4];
  #pragma unroll
  for (int m = 0; m < 4; m++)
    #pragma unroll
    for (int n = 0; n < 4; n++) acc[m][n] = (f32x4)0.0f;

  #pragma unroll
  for (int kk = 0; kk < 4; kk++) {
    short8 af[4], bfr[4];
    #pragma unroll
    for (int m = 0; m < 4; m++)
      af[m] = *reinterpret_cast<const short8*>(
          ww + (size_t)(wave * 64 + m * 16 + lr) * 128 + kk * 32 + lg * 8);
    #pragma unroll
    for (int n = 0; n < 4; n++)
      bfr[n] = *reinterpret_cast<const short8*>(&y_s[n * 16 + lr][kk * 32 + lg * 8]);
    #pragma unroll
    for (int m = 0; m < 4; m++)
      #pragma unroll
      for (int n = 0; n < 4; n++)
        acc[m][n] = MFMA16(af[m], bfr[n], acc[m][n]);
  }

  #pragma unroll
  for (int m = 0; m < 4; m++) {
    #pragma unroll
    for (int n = 0; n < 4; n++) {
      #pragma unroll
      for (int r = 0; r < 4; r++) {
        int co = wave * 64 + m * 16 + lg * 4 + r;
        int q = q0 + n * 16 + lr;
        size_t oidx = ((size_t)b * 256 + co) * 4096 + q;
        float v = acc[m][n][r] * sc_s[co] + sh_s[co];
        out[oidx] = v + x[oidx];
      }
    }
  }
}

// ---------------------------------------------------------------------------
extern "C" void kernel_launch(void* const* d_in, const int* in_sizes, int n_in,
                              void* d_out, int out_size, void* d_ws, size_t ws_size,
                              hipStream_t stream)
{
  const float* x    = (const float*)d_in[0];
  const float* nb   = (const float*)d_in[1];
  const float* g_w  = (const float*)d_in[2];
  const float* g_b  = (const float*)d_in[3];
  const float* th_w = (const float*)d_in[4];
  const float* th_b = (const float*)d_in[5];
  const float* ph_w = (const float*)d_in[6];
  const float* ph_b = (const float*)d_in[7];
  const float* w_w  = (const float*)d_in[8];
  const float* w_b  = (const float*)d_in[9];
  const float* gam  = (const float*)d_in[10];
  const float* bet  = (const float*)d_in[11];
  const float* mu   = (const float*)d_in[12];
  const float* var  = (const float*)d_in[13];
  float* out = (float*)d_out;

  char* ws = (char*)d_ws;
  short* theta_full = (short*)(ws);                        // 8 MB  [b][4096][128]
  short* phi_full   = (short*)(ws + (size_t)(8u << 20));   // 8 MB  [b][4096][128]
  short* g_full     = (short*)(ws + (size_t)(16u << 20));  // 8 MB  [b][4096][128]
  short* phi_kc     = (short*)(ws + (size_t)(24u << 20));  // 2 MB  [b][1024][128]
  short* g_ck       = (short*)(ws + (size_t)(26u << 20));  // 2 MB  [b][128][1024]
  short* yb         = (short*)(ws + (size_t)(28u << 20));  // 8 MB  [b][4096][128]
  short* wts        = (short*)(ws + (size_t)(36u << 20));  // 256KB: th, ph, g, w
  short* th_wb = wts;
  short* ph_wb = wts + 32768;
  short* g_wb  = wts + 2 * 32768;
  short* w_wb  = wts + 3 * 32768;

  cvt_w<<<dim3(32, 4), 256, 0, stream>>>(th_w, ph_w, g_w, w_w, wts);
  conv_proj<2><<<dim3(64, 8), 256, 0, stream>>>(nb, th_wb, th_b, ph_wb, ph_b,
                                                theta_full, phi_full);
  conv_proj<1><<<dim3(64, 8), 256, 0, stream>>>(x, g_wb, g_b, nullptr, nullptr,
                                                g_full, nullptr);
  pool_phi_k<<<dim3(64, 8), 256, 0, stream>>>(phi_full, phi_kc);
  pool_g_t<<<dim3(32, 8), 256, 0, stream>>>(g_full, g_ck);
  attn<<<dim3(32, 8), 256, 0, stream>>>(theta_full, phi_kc, g_ck, yb);
  wconv_bn<<<dim3(64, 8), 256, 0, stream>>>(yb, w_wb, w_b, gam, bet, mu, var, x, out);
}